// Round 3
// baseline (298.806 us; speedup 1.0000x reference)
//
#include <hip/hip_runtime.h>
#include <hip/hip_bf16.h>

// Problem: B=2, L=2048, D=1024, H=16, HD=64. causal self-attention block.
// out = proj(attn(qkv(x)))
//
// Workspace layout (needs 48 MB):
//   [0,8M)   x_bf16      (4096,1024)
//   [8,14M)  WqkvT bf16  (3072,1024)   W^T so GEMM B-operand is [n][k]
//   [14,16M) WprojT bf16 (1024,1024)
//   [16,24M) q bf16 (B,H,L,HD)  pre-scaled by 1/8
//   [24,32M) k bf16 (B,H,L,HD)
//   [32,40M) vT bf16 (B,H,HD,L)
//   [40,48M) O bf16 (B,L,H*HD) = (4096,1024)

typedef __attribute__((ext_vector_type(8))) short s16x8;
typedef __attribute__((ext_vector_type(4))) float f32x4;

__device__ __forceinline__ unsigned short f2b(float f) {
  __hip_bfloat16 h = __float2bfloat16(f);
  return *reinterpret_cast<unsigned short*>(&h);
}

// async global->LDS, 16B per lane. LDS dest is wave-uniform base (HW writes
// base + lane*16); global src is per-lane. NOTE: the LDS pointer must be
// converted via addrspacecast (direct pointer cast) — truncating the flat
// address to 32 bits is WRONG (flat LDS addrs are aperture-based).
__device__ __forceinline__ void gl_lds16(const void* g, void* l) {
  __builtin_amdgcn_global_load_lds(
      (const __attribute__((address_space(1))) unsigned int*)g,
      (__attribute__((address_space(3))) unsigned int*)l,
      16, 0, 0);
}

// ---------------- converts ----------------

__global__ __launch_bounds__(256) void convert_f32_bf16(
    const float* __restrict__ in, unsigned short* __restrict__ out, int n4) {
  int i = blockIdx.x * 256 + threadIdx.x;
  if (i >= n4) return;
  float4 v = reinterpret_cast<const float4*>(in)[i];
  ushort4 o;
  o.x = f2b(v.x); o.y = f2b(v.y); o.z = f2b(v.z); o.w = f2b(v.w);
  reinterpret_cast<ushort4*>(out)[i] = o;
}

// out[c][r] = (bf16) in[r][c];  in is (R,C) fp32, out is (C,R) bf16
__global__ __launch_bounds__(256) void transpose_f32_bf16(
    const float* __restrict__ in, unsigned short* __restrict__ out, int R, int C) {
  __shared__ float tile[32][33];
  int cb = blockIdx.x * 32, rb = blockIdx.y * 32;
  int tx = threadIdx.x, ty = threadIdx.y;
  #pragma unroll
  for (int i = ty; i < 32; i += 8)
    tile[i][tx] = in[(size_t)(rb + i) * C + cb + tx];
  __syncthreads();
  #pragma unroll
  for (int i = ty; i < 32; i += 8)
    out[(size_t)(cb + i) * R + rb + tx] = f2b(tile[tx][i]);
}

// ---------------- GEMM 128x128 tile, K=1024, BK=64 ----------------
// A (M,1024) bf16 row-major; Bt (N,1024) bf16 row-major (= B^T).
// MODE 0: QKV epilogue (scatter q/k/vT, q scaled). MODE 1: fp32 out + bias.
template <int MODE>
__global__ __launch_bounds__(256) void gemm128(
    const unsigned short* __restrict__ A, const unsigned short* __restrict__ Bt,
    const float* __restrict__ bias, unsigned short* __restrict__ qOut,
    unsigned short* __restrict__ kOut, unsigned short* __restrict__ vOut,
    float* __restrict__ fOut) {
  __shared__ char sA[16384];
  __shared__ char sB[16384];
  const int tid = threadIdx.x;
  const int wid = tid >> 6, lane = tid & 63;
  const int lg = lane >> 4, lr = lane & 15;
  const int wr = wid >> 1, wc = wid & 1;
  const int mb = blockIdx.y, nb = blockIdx.x;

  f32x4 acc[4][4];
  #pragma unroll
  for (int i = 0; i < 4; ++i)
    #pragma unroll
    for (int j = 0; j < 4; ++j) acc[i][j] = f32x4{0.f, 0.f, 0.f, 0.f};

  for (int ks = 0; ks < 16; ++ks) {
    __syncthreads();
    // stage A,Bt tiles (16KB each): LDS linear, global source pre-swizzled
    #pragma unroll
    for (int r = 0; r < 4; ++r) {
      const int chunk = r * 4 + wid;
      const int o = chunk * 1024 + lane * 16;
      const int row = o >> 7;              // tile row 0..127
      const int c16 = (o >> 4) & 7;        // 16B slot within 128B row
      const int swz = (c16 ^ (row & 7)) << 4;
      gl_lds16((const char*)A + ((size_t)(mb * 128 + row) * 1024 + ks * 64) * 2 + swz,
               sA + chunk * 1024);
      gl_lds16((const char*)Bt + ((size_t)(nb * 128 + row) * 1024 + ks * 64) * 2 + swz,
               sB + chunk * 1024);
    }
    __syncthreads();
    #pragma unroll
    for (int kb = 0; kb < 2; ++kb) {
      s16x8 af[4], bfr[4];
      #pragma unroll
      for (int mt = 0; mt < 4; ++mt) {
        const int rrow = wr * 64 + mt * 16 + lr;
        const int off = kb * 64 + lg * 16;
        af[mt] = *(const s16x8*)(sA + rrow * 128 + (off ^ ((rrow & 7) << 4)));
      }
      #pragma unroll
      for (int nt = 0; nt < 4; ++nt) {
        const int rrow = wc * 64 + nt * 16 + lr;
        const int off = kb * 64 + lg * 16;
        bfr[nt] = *(const s16x8*)(sB + rrow * 128 + (off ^ ((rrow & 7) << 4)));
      }
      #pragma unroll
      for (int mt = 0; mt < 4; ++mt)
        #pragma unroll
        for (int nt = 0; nt < 4; ++nt)
          acc[mt][nt] = __builtin_amdgcn_mfma_f32_16x16x32_bf16(
              af[mt], bfr[nt], acc[mt][nt], 0, 0, 0);
    }
  }

  // epilogue. C layout: col = lane&15, row = (lane>>4)*4 + r
  #pragma unroll
  for (int mt = 0; mt < 4; ++mt)
    #pragma unroll
    for (int nt = 0; nt < 4; ++nt)
      #pragma unroll
      for (int r = 0; r < 4; ++r) {
        const int m = mb * 128 + wr * 64 + mt * 16 + lg * 4 + r;
        const int n = nb * 128 + wc * 64 + nt * 16 + lr;
        float val = acc[mt][nt][r] + bias[n];
        if constexpr (MODE == 0) {
          const int b = m >> 11, ml = m & 2047;
          if (n < 1024) {           // q, scaled by HD^-0.5
            const int h = n >> 6, d = n & 63;
            qOut[((size_t)((b * 16 + h) * 2048 + ml)) * 64 + d] = f2b(val * 0.125f);
          } else if (n < 2048) {    // k
            const int nn = n - 1024, h = nn >> 6, d = nn & 63;
            kOut[((size_t)((b * 16 + h) * 2048 + ml)) * 64 + d] = f2b(val);
          } else {                  // v -> transposed (B,H,HD,L)
            const int nn = n - 2048, h = nn >> 6, d = nn & 63;
            vOut[((size_t)((b * 16 + h) * 64 + d)) * 2048 + ml] = f2b(val);
          }
        } else {
          fOut[(size_t)m * 1024 + n] = val;
        }
      }
}

// ---------------- flash attention ----------------
// grid: 32 (b,h) * 16 q-tiles. block 256 = 4 waves, 32 q-rows/wave. KVBLK=64.
__global__ __launch_bounds__(256) void attn_fwd(
    const unsigned short* __restrict__ Q, const unsigned short* __restrict__ Kb,
    const unsigned short* __restrict__ Vt, unsigned short* __restrict__ O) {
  __shared__ char sK[8192];    // K tile [64 kv][64 d], swizzled
  __shared__ char sV[8192];    // V^T tile [64 d][64 kv], swizzled
  __shared__ char sP[16384];   // per-wave P [32][64], swizzled
  const int bid = blockIdx.x;
  const int bh = bid >> 4;     // 0..31
  const int qi = bid & 15;     // q-tile
  const int b = bh >> 4, h = bh & 15;
  const int tid = threadIdx.x, wid = tid >> 6, lane = tid & 63;
  const int lg = lane >> 4, lr = lane & 15;
  const float LOG2E = 1.4426950408889634f;

  // Q fragments live in registers for the whole block
  s16x8 qf[2][2];
  #pragma unroll
  for (int mt = 0; mt < 2; ++mt)
    #pragma unroll
    for (int kb = 0; kb < 2; ++kb) {
      const int row = qi * 128 + wid * 32 + mt * 16 + lr;
      qf[mt][kb] = *(const s16x8*)((const char*)Q +
          ((size_t)(bh * 2048 + row) * 64 + kb * 32 + lg * 8) * 2);
    }

  f32x4 acc[2][4];
  #pragma unroll
  for (int i = 0; i < 2; ++i)
    #pragma unroll
    for (int j = 0; j < 4; ++j) acc[i][j] = f32x4{0.f, 0.f, 0.f, 0.f};
  float rm[2][4], rl[2][4];
  #pragma unroll
  for (int i = 0; i < 2; ++i)
    #pragma unroll
    for (int j = 0; j < 4; ++j) { rm[i][j] = -INFINITY; rl[i][j] = 0.f; }

  const int q_max = qi * 128 + wid * 32 + 31;
  const int nkv = (qi + 1) * 2;

  for (int t = 0; t < nkv; ++t) {
    const int kv0 = t * 64;
    __syncthreads();
    #pragma unroll
    for (int r = 0; r < 2; ++r) {
      const int chunk = r * 4 + wid;
      const int o = chunk * 1024 + lane * 16;
      const int row = o >> 7;
      const int c16 = (o >> 4) & 7;
      const int swz = (c16 ^ (row & 7)) << 4;
      gl_lds16((const char*)Kb + ((size_t)(bh * 2048 + kv0 + row) * 64) * 2 + swz,
               sK + chunk * 1024);
      gl_lds16((const char*)Vt + ((size_t)(bh * 64 + row) * 2048 + kv0) * 2 + swz,
               sV + chunk * 1024);
    }
    __syncthreads();
    if (kv0 > q_max) continue;  // fully masked for this wave; barriers stay aligned

    // S = Q K^T  (S[q][kv], 32x64 per wave)
    f32x4 sfr[2][4];
    #pragma unroll
    for (int i = 0; i < 2; ++i)
      #pragma unroll
      for (int j = 0; j < 4; ++j) sfr[i][j] = f32x4{0.f, 0.f, 0.f, 0.f};
    #pragma unroll
    for (int kb = 0; kb < 2; ++kb) {
      s16x8 kf[4];
      #pragma unroll
      for (int nt = 0; nt < 4; ++nt) {
        const int krow = nt * 16 + lr;
        const int off = kb * 64 + lg * 16;
        kf[nt] = *(const s16x8*)(sK + krow * 128 + (off ^ ((krow & 7) << 4)));
      }
      #pragma unroll
      for (int mt = 0; mt < 2; ++mt)
        #pragma unroll
        for (int nt = 0; nt < 4; ++nt)
          sfr[mt][nt] = __builtin_amdgcn_mfma_f32_16x16x32_bf16(
              qf[mt][kb], kf[nt], sfr[mt][nt], 0, 0, 0);
    }

    // mask + online softmax (row-reduce across 16-lane groups)
    char* wbase = sP + wid * 4096;
    #pragma unroll
    for (int mt = 0; mt < 2; ++mt) {
      #pragma unroll
      for (int r = 0; r < 4; ++r) {
        const int grow = qi * 128 + wid * 32 + mt * 16 + lg * 4 + r;
        float tmax = -INFINITY;
        #pragma unroll
        for (int nt = 0; nt < 4; ++nt) {
          const int col = kv0 + nt * 16 + lr;
          float s = sfr[mt][nt][r];
          if (col > grow) s = -INFINITY;
          sfr[mt][nt][r] = s;
          tmax = fmaxf(tmax, s);
        }
        tmax = fmaxf(tmax, __shfl_xor(tmax, 1));
        tmax = fmaxf(tmax, __shfl_xor(tmax, 2));
        tmax = fmaxf(tmax, __shfl_xor(tmax, 4));
        tmax = fmaxf(tmax, __shfl_xor(tmax, 8));
        const float mold = rm[mt][r];
        const float mnew = fmaxf(mold, tmax);
        const float alpha = exp2f((mold - mnew) * LOG2E);
        float psum = 0.f;
        #pragma unroll
        for (int nt = 0; nt < 4; ++nt) {
          const float p = exp2f((sfr[mt][nt][r] - mnew) * LOG2E);
          sfr[mt][nt][r] = p;
          psum += p;
        }
        psum += __shfl_xor(psum, 1);
        psum += __shfl_xor(psum, 2);
        psum += __shfl_xor(psum, 4);
        psum += __shfl_xor(psum, 8);
        rl[mt][r] = rl[mt][r] * alpha + psum;
        rm[mt][r] = mnew;
        #pragma unroll
        for (int nt = 0; nt < 4; ++nt) acc[mt][nt][r] *= alpha;
        // write P row to per-wave LDS (C-layout -> memory), swizzled
        const int prow = mt * 16 + lg * 4 + r;
        #pragma unroll
        for (int nt = 0; nt < 4; ++nt) {
          const int pcolb = nt * 32 + lr * 2;
          *(unsigned short*)(wbase + prow * 128 + (pcolb ^ ((prow & 7) << 4))) =
              f2b(sfr[mt][nt][r]);
        }
      }
    }

    // PV: O += P V. P read back as A-fragments; V^T rows give B-fragments.
    s16x8 pf[2][2], vf[4][2];
    #pragma unroll
    for (int mt = 0; mt < 2; ++mt)
      #pragma unroll
      for (int kb = 0; kb < 2; ++kb) {
        const int prow = mt * 16 + lr;
        const int off = kb * 64 + lg * 16;
        pf[mt][kb] = *(const s16x8*)(wbase + prow * 128 + (off ^ ((prow & 7) << 4)));
      }
    #pragma unroll
    for (int nt = 0; nt < 4; ++nt)
      #pragma unroll
      for (int kb = 0; kb < 2; ++kb) {
        const int vrow = nt * 16 + lr;
        const int off = kb * 64 + lg * 16;
        vf[nt][kb] = *(const s16x8*)(sV + vrow * 128 + (off ^ ((vrow & 7) << 4)));
      }
    #pragma unroll
    for (int mt = 0; mt < 2; ++mt)
      #pragma unroll
      for (int nt = 0; nt < 4; ++nt)
        #pragma unroll
        for (int kb = 0; kb < 2; ++kb)
          acc[mt][nt] = __builtin_amdgcn_mfma_f32_16x16x32_bf16(
              pf[mt][kb], vf[nt][kb], acc[mt][nt], 0, 0, 0);
  }

  // epilogue: O[b][l][h*64+d] = acc / l
  #pragma unroll
  for (int mt = 0; mt < 2; ++mt)
    #pragma unroll
    for (int nt = 0; nt < 4; ++nt)
      #pragma unroll
      for (int r = 0; r < 4; ++r) {
        const int grow = qi * 128 + wid * 32 + mt * 16 + lg * 4 + r;
        const int d = nt * 16 + lr;
        const float v = acc[mt][nt][r] / rl[mt][r];
        O[(size_t)(b * 2048 + grow) * 1024 + h * 64 + d] = f2b(v);
      }
}

// ---------------- launch ----------------

extern "C" void kernel_launch(void* const* d_in, const int* in_sizes, int n_in,
                              void* d_out, int out_size, void* d_ws, size_t ws_size,
                              hipStream_t stream) {
  const float* x     = (const float*)d_in[0];
  const float* Wqkv  = (const float*)d_in[1];
  const float* bqkv  = (const float*)d_in[2];
  const float* Wproj = (const float*)d_in[3];
  const float* bproj = (const float*)d_in[4];
  float* out = (float*)d_out;

  char* ws = (char*)d_ws;
  unsigned short* xb    = (unsigned short*)(ws);
  unsigned short* wqkvt = (unsigned short*)(ws + (8ull << 20));
  unsigned short* wprjt = (unsigned short*)(ws + (14ull << 20));
  unsigned short* qb    = (unsigned short*)(ws + (16ull << 20));
  unsigned short* kb    = (unsigned short*)(ws + (24ull << 20));
  unsigned short* vT    = (unsigned short*)(ws + (32ull << 20));
  unsigned short* Ob    = (unsigned short*)(ws + (40ull << 20));

  // x: 4096*1024 = 4,194,304 elems = 1,048,576 float4
  convert_f32_bf16<<<4096, 256, 0, stream>>>(x, xb, 1048576);
  transpose_f32_bf16<<<dim3(96, 32), dim3(32, 8), 0, stream>>>(Wqkv, wqkvt, 1024, 3072);
  transpose_f32_bf16<<<dim3(32, 32), dim3(32, 8), 0, stream>>>(Wproj, wprjt, 1024, 1024);
  gemm128<0><<<dim3(24, 32), 256, 0, stream>>>(xb, wqkvt, bqkv, qb, kb, vT, nullptr);
  attn_fwd<<<512, 256, 0, stream>>>(qb, kb, vT, Ob);
  gemm128<1><<<dim3(8, 32), 256, 0, stream>>>(Ob, wprjt, bproj, nullptr, nullptr, nullptr, out);
}

// Round 4
// 297.563 us; speedup vs baseline: 1.0042x; 1.0042x over previous
//
#include <hip/hip_runtime.h>
#include <hip/hip_bf16.h>

// Problem: B=2, L=2048, D=1024, H=16, HD=64. causal self-attention block.
// out = proj(attn(qkv(x)))
//
// Workspace layout (needs 48 MB):
//   [0,8M)   x_bf16      (4096,1024)
//   [8,14M)  WqkvT bf16  (3072,1024)   W^T so GEMM B-operand is [n][k]
//   [14,16M) WprojT bf16 (1024,1024)
//   [16,24M) q bf16 (B,H,L,HD)  pre-scaled by LOG2E/8 (softmax in base-2)
//   [24,32M) k bf16 (B,H,L,HD)
//   [32,40M) vT bf16 (B,H,HD,L)
//   [40,48M) O bf16 (B,L,H*HD) = (4096,1024)

typedef __attribute__((ext_vector_type(8))) short s16x8;
typedef __attribute__((ext_vector_type(4))) float f32x4;

__device__ __forceinline__ unsigned short f2b(float f) {
  __hip_bfloat16 h = __float2bfloat16(f);
  return *reinterpret_cast<unsigned short*>(&h);
}

// async global->LDS, 16B per lane. LDS dest is wave-uniform base (HW writes
// base + lane*16); global src is per-lane. Pointer cast = addrspacecast.
__device__ __forceinline__ void gl_lds16(const void* g, void* l) {
  __builtin_amdgcn_global_load_lds(
      (const __attribute__((address_space(1))) unsigned int*)g,
      (__attribute__((address_space(3))) unsigned int*)l,
      16, 0, 0);
}

// ---------------- converts ----------------

__global__ __launch_bounds__(256) void convert_f32_bf16(
    const float* __restrict__ in, unsigned short* __restrict__ out, int n4) {
  int i = blockIdx.x * 256 + threadIdx.x;
  if (i >= n4) return;
  float4 v = reinterpret_cast<const float4*>(in)[i];
  ushort4 o;
  o.x = f2b(v.x); o.y = f2b(v.y); o.z = f2b(v.z); o.w = f2b(v.w);
  reinterpret_cast<ushort4*>(out)[i] = o;
}

// out[c][r] = (bf16) in[r][c];  in is (R,C) fp32, out is (C,R) bf16
__global__ __launch_bounds__(256) void transpose_f32_bf16(
    const float* __restrict__ in, unsigned short* __restrict__ out, int R, int C) {
  __shared__ float tile[32][33];
  int cb = blockIdx.x * 32, rb = blockIdx.y * 32;
  int tx = threadIdx.x, ty = threadIdx.y;
  #pragma unroll
  for (int i = ty; i < 32; i += 8)
    tile[i][tx] = in[(size_t)(rb + i) * C + cb + tx];
  __syncthreads();
  #pragma unroll
  for (int i = ty; i < 32; i += 8)
    out[(size_t)(cb + i) * R + rb + tx] = f2b(tile[tx][i]);
}

// ---------------- GEMM 128x128 tile, K=1024, BK=64 ----------------
// A (M,1024) bf16 row-major; Bt (N,1024) bf16 row-major (= B^T).
// MODE 0: QKV epilogue (scatter q/k/vT, q scaled). MODE 1: fp32 out + bias.
template <int MODE>
__global__ __launch_bounds__(256) void gemm128(
    const unsigned short* __restrict__ A, const unsigned short* __restrict__ Bt,
    const float* __restrict__ bias, unsigned short* __restrict__ qOut,
    unsigned short* __restrict__ kOut, unsigned short* __restrict__ vOut,
    float* __restrict__ fOut) {
  __shared__ char sA[16384];
  __shared__ char sB[16384];
  const int tid = threadIdx.x;
  const int wid = tid >> 6, lane = tid & 63;
  const int lg = lane >> 4, lr = lane & 15;
  const int wr = wid >> 1, wc = wid & 1;
  const int mb = blockIdx.y, nb = blockIdx.x;

  f32x4 acc[4][4];
  #pragma unroll
  for (int i = 0; i < 4; ++i)
    #pragma unroll
    for (int j = 0; j < 4; ++j) acc[i][j] = f32x4{0.f, 0.f, 0.f, 0.f};

  for (int ks = 0; ks < 16; ++ks) {
    __syncthreads();
    // stage A,Bt tiles (16KB each): LDS linear, global source pre-swizzled
    #pragma unroll
    for (int r = 0; r < 4; ++r) {
      const int chunk = r * 4 + wid;
      const int o = chunk * 1024 + lane * 16;
      const int row = o >> 7;              // tile row 0..127
      const int c16 = (o >> 4) & 7;        // 16B slot within 128B row
      const int swz = (c16 ^ (row & 7)) << 4;
      gl_lds16((const char*)A + ((size_t)(mb * 128 + row) * 1024 + ks * 64) * 2 + swz,
               sA + chunk * 1024);
      gl_lds16((const char*)Bt + ((size_t)(nb * 128 + row) * 1024 + ks * 64) * 2 + swz,
               sB + chunk * 1024);
    }
    __syncthreads();
    #pragma unroll
    for (int kb = 0; kb < 2; ++kb) {
      s16x8 af[4], bfr[4];
      #pragma unroll
      for (int mt = 0; mt < 4; ++mt) {
        const int rrow = wr * 64 + mt * 16 + lr;
        const int off = kb * 64 + lg * 16;
        af[mt] = *(const s16x8*)(sA + rrow * 128 + (off ^ ((rrow & 7) << 4)));
      }
      #pragma unroll
      for (int nt = 0; nt < 4; ++nt) {
        const int rrow = wc * 64 + nt * 16 + lr;
        const int off = kb * 64 + lg * 16;
        bfr[nt] = *(const s16x8*)(sB + rrow * 128 + (off ^ ((rrow & 7) << 4)));
      }
      #pragma unroll
      for (int mt = 0; mt < 4; ++mt)
        #pragma unroll
        for (int nt = 0; nt < 4; ++nt)
          acc[mt][nt] = __builtin_amdgcn_mfma_f32_16x16x32_bf16(
              af[mt], bfr[nt], acc[mt][nt], 0, 0, 0);
    }
  }

  // epilogue. C layout: col = lane&15, row = (lane>>4)*4 + r
  #pragma unroll
  for (int mt = 0; mt < 4; ++mt)
    #pragma unroll
    for (int nt = 0; nt < 4; ++nt)
      #pragma unroll
      for (int r = 0; r < 4; ++r) {
        const int m = mb * 128 + wr * 64 + mt * 16 + lg * 4 + r;
        const int n = nb * 128 + wc * 64 + nt * 16 + lr;
        float val = acc[mt][nt][r] + bias[n];
        if constexpr (MODE == 0) {
          const int b = m >> 11, ml = m & 2047;
          if (n < 1024) {           // q, scaled by HD^-0.5 * LOG2E (base-2 softmax)
            const int h = n >> 6, d = n & 63;
            qOut[((size_t)((b * 16 + h) * 2048 + ml)) * 64 + d] =
                f2b(val * 0.18033688f);
          } else if (n < 2048) {    // k
            const int nn = n - 1024, h = nn >> 6, d = nn & 63;
            kOut[((size_t)((b * 16 + h) * 2048 + ml)) * 64 + d] = f2b(val);
          } else {                  // v -> transposed (B,H,HD,L)
            const int nn = n - 2048, h = nn >> 6, d = nn & 63;
            vOut[((size_t)((b * 16 + h) * 64 + d)) * 2048 + ml] = f2b(val);
          }
        } else {
          fOut[(size_t)m * 1024 + n] = val;
        }
      }
}

// ---------------- flash attention ----------------
// 2048 independent single-wave blocks (64 thr). Each wave owns 32 q-rows and
// loops exactly its own kv tiles. K/V read direct from global (L2-resident:
// 512KB/head; blocks clustered so each XCD's L2 serves 4 heads). No barriers.
// Heavy q-segments launch first (load balance). Softmax in base-2 domain
// (q pre-scaled by LOG2E/8). sP = per-wave P round-trip LDS, 4KB, swizzled.
__global__ __launch_bounds__(64) void attn_fwd(
    const unsigned short* __restrict__ Q, const unsigned short* __restrict__ Kb,
    const unsigned short* __restrict__ Vt, unsigned short* __restrict__ O) {
  __shared__ char sP[4096];   // [32 q][64 kv] bf16, XOR-swizzled
  const int bid = blockIdx.x;
  const int j = bid >> 3;
  const int bh = (bid & 7) * 4 + (j >> 6);  // cluster 4 heads per XCD slot
  const int qseg = 63 - (j & 63);           // heavy-first
  const int b = bh >> 4, h = bh & 15;
  const int lane = threadIdx.x;
  const int lg = lane >> 4, lr = lane & 15;
  const int base = qseg * 32;

  // Q fragments (A-frag: row = lane&15, k = (lane>>4)*8+i)
  s16x8 qf[2][2];
  #pragma unroll
  for (int mt = 0; mt < 2; ++mt)
    #pragma unroll
    for (int kb = 0; kb < 2; ++kb) {
      const int row = base + mt * 16 + lr;
      qf[mt][kb] = *(const s16x8*)(Q + (size_t)(bh * 2048 + row) * 64 + kb * 32 + lg * 8);
    }

  f32x4 acc[2][4];
  float rm[2][4], rl[2][4];
  #pragma unroll
  for (int i = 0; i < 2; ++i)
    #pragma unroll
    for (int jj = 0; jj < 4; ++jj) {
      acc[i][jj] = f32x4{0.f, 0.f, 0.f, 0.f};
      rm[i][jj] = -INFINITY;
      rl[i][jj] = 0.f;
    }

  const int nkv = (qseg >> 1) + 1;
  for (int t = 0; t < nkv; ++t) {
    const int kv0 = t * 64;

    // S = Q K^T  (32 q x 64 kv)
    f32x4 sfr[2][4];
    #pragma unroll
    for (int i = 0; i < 2; ++i)
      #pragma unroll
      for (int jj = 0; jj < 4; ++jj) sfr[i][jj] = f32x4{0.f, 0.f, 0.f, 0.f};
    #pragma unroll
    for (int kb = 0; kb < 2; ++kb) {
      s16x8 kf[4];
      #pragma unroll
      for (int nt = 0; nt < 4; ++nt)
        kf[nt] = *(const s16x8*)(Kb +
            (size_t)(bh * 2048 + kv0 + nt * 16 + lr) * 64 + kb * 32 + lg * 8);
      #pragma unroll
      for (int mt = 0; mt < 2; ++mt)
        #pragma unroll
        for (int nt = 0; nt < 4; ++nt)
          sfr[mt][nt] = __builtin_amdgcn_mfma_f32_16x16x32_bf16(
              qf[mt][kb], kf[nt], sfr[mt][nt], 0, 0, 0);
    }

    // issue V loads now so they overlap the softmax VALU chain
    s16x8 vf[2][4];
    #pragma unroll
    for (int kb = 0; kb < 2; ++kb)
      #pragma unroll
      for (int nt = 0; nt < 4; ++nt)
        vf[kb][nt] = *(const s16x8*)(Vt +
            (size_t)(bh * 64 + nt * 16 + lr) * 2048 + kv0 + kb * 32 + lg * 8);

    // mask + online softmax (base-2: S already scaled by LOG2E)
    #pragma unroll
    for (int mt = 0; mt < 2; ++mt) {
      #pragma unroll
      for (int r = 0; r < 4; ++r) {
        const int grow = base + mt * 16 + lg * 4 + r;
        float tmax = -INFINITY;
        #pragma unroll
        for (int nt = 0; nt < 4; ++nt) {
          const int col = kv0 + nt * 16 + lr;
          float s = sfr[mt][nt][r];
          if (col > grow) s = -INFINITY;
          sfr[mt][nt][r] = s;
          tmax = fmaxf(tmax, s);
        }
        tmax = fmaxf(tmax, __shfl_xor(tmax, 1));
        tmax = fmaxf(tmax, __shfl_xor(tmax, 2));
        tmax = fmaxf(tmax, __shfl_xor(tmax, 4));
        tmax = fmaxf(tmax, __shfl_xor(tmax, 8));
        const float mold = rm[mt][r];
        const float mnew = fmaxf(mold, tmax);
        const float alpha = exp2f(mold - mnew);
        float psum = 0.f;
        #pragma unroll
        for (int nt = 0; nt < 4; ++nt) {
          const float p = exp2f(sfr[mt][nt][r] - mnew);
          sfr[mt][nt][r] = p;
          psum += p;
        }
        psum += __shfl_xor(psum, 1);
        psum += __shfl_xor(psum, 2);
        psum += __shfl_xor(psum, 4);
        psum += __shfl_xor(psum, 8);
        rl[mt][r] = rl[mt][r] * alpha + psum;
        rm[mt][r] = mnew;
        #pragma unroll
        for (int nt = 0; nt < 4; ++nt) acc[mt][nt][r] *= alpha;
        // write P row (C-layout -> LDS), swizzled
        const int prow = mt * 16 + lg * 4 + r;
        #pragma unroll
        for (int nt = 0; nt < 4; ++nt) {
          const int pcolb = nt * 32 + lr * 2;
          *(unsigned short*)(sP + prow * 128 + (pcolb ^ ((prow & 7) << 4))) =
              f2b(sfr[mt][nt][r]);
        }
      }
    }

    // PV: O += P V. P read back as A-fragments; vT rows give B-fragments.
    s16x8 pf[2][2];
    #pragma unroll
    for (int mt = 0; mt < 2; ++mt)
      #pragma unroll
      for (int kb = 0; kb < 2; ++kb) {
        const int prow = mt * 16 + lr;
        const int off = kb * 64 + lg * 16;
        pf[mt][kb] = *(const s16x8*)(sP + prow * 128 + (off ^ ((prow & 7) << 4)));
      }
    #pragma unroll
    for (int mt = 0; mt < 2; ++mt)
      #pragma unroll
      for (int nt = 0; nt < 4; ++nt)
        #pragma unroll
        for (int kb = 0; kb < 2; ++kb)
          acc[mt][nt] = __builtin_amdgcn_mfma_f32_16x16x32_bf16(
              pf[mt][kb], vf[kb][nt], acc[mt][nt], 0, 0, 0);
  }

  // epilogue: O[b][l][h*64+d] = acc / l
  #pragma unroll
  for (int mt = 0; mt < 2; ++mt)
    #pragma unroll
    for (int nt = 0; nt < 4; ++nt)
      #pragma unroll
      for (int r = 0; r < 4; ++r) {
        const int grow = base + mt * 16 + lg * 4 + r;
        const int d = nt * 16 + lr;
        const float v = acc[mt][nt][r] / rl[mt][r];
        O[(size_t)(b * 2048 + grow) * 1024 + h * 64 + d] = f2b(v);
      }
}

// ---------------- launch ----------------

extern "C" void kernel_launch(void* const* d_in, const int* in_sizes, int n_in,
                              void* d_out, int out_size, void* d_ws, size_t ws_size,
                              hipStream_t stream) {
  const float* x     = (const float*)d_in[0];
  const float* Wqkv  = (const float*)d_in[1];
  const float* bqkv  = (const float*)d_in[2];
  const float* Wproj = (const float*)d_in[3];
  const float* bproj = (const float*)d_in[4];
  float* out = (float*)d_out;

  char* ws = (char*)d_ws;
  unsigned short* xb    = (unsigned short*)(ws);
  unsigned short* wqkvt = (unsigned short*)(ws + (8ull << 20));
  unsigned short* wprjt = (unsigned short*)(ws + (14ull << 20));
  unsigned short* qb    = (unsigned short*)(ws + (16ull << 20));
  unsigned short* kb    = (unsigned short*)(ws + (24ull << 20));
  unsigned short* vT    = (unsigned short*)(ws + (32ull << 20));
  unsigned short* Ob    = (unsigned short*)(ws + (40ull << 20));

  // x: 4096*1024 = 4,194,304 elems = 1,048,576 float4
  convert_f32_bf16<<<4096, 256, 0, stream>>>(x, xb, 1048576);
  transpose_f32_bf16<<<dim3(96, 32), dim3(32, 8), 0, stream>>>(Wqkv, wqkvt, 1024, 3072);
  transpose_f32_bf16<<<dim3(32, 32), dim3(32, 8), 0, stream>>>(Wproj, wprjt, 1024, 1024);
  gemm128<0><<<dim3(24, 32), 256, 0, stream>>>(xb, wqkvt, bqkv, qb, kb, vT, nullptr);
  attn_fwd<<<2048, 64, 0, stream>>>(qb, kb, vT, Ob);
  gemm128<1><<<dim3(8, 32), 256, 0, stream>>>(Ob, wprjt, bproj, nullptr, nullptr, nullptr, out);
}